// Round 7
// baseline (175.071 us; speedup 1.0000x reference)
//
#include <hip/hip_runtime.h>
#include <hip/hip_cooperative_groups.h>
#include <math.h>

namespace cg = cooperative_groups;

// ClownSelector R16: fused cooperative (dots + grid.sync + top2), pad-68.
//
// R15 post-mortem: scalar-proto k-loop confirmed (VGPR 28, SGPR 112, no
// spills, VALUBusy 45%) but (a) staging ds_write banks (k*64, 64=0 mod 32)
// = 4-way conflict (1.57M), (b) token-per-lane + SGPR-proto REQUIRES 64
// lanes = 64 tokens -> grid pinned at 256 = 4 waves/SIMD; ~5 in-flight
// s_load_dwordx16 covers ~170cyc of ~250cyc L2 latency -> ~46% busy ceiling.
// Meanwhile total - rd has been a CONSTANT ~80us across R9-R15: launch
// overhead + the half-idle top2 (grid 128). That's now the biggest lever.
//
// R16: (1) xt stride 64 -> 68: write banks (4k+st)%32 collapse to 2-way
// (free, m136); read (4kk+lane)%32 stays free. (2) Fuse top2 into the dots
// kernel via hipLaunchCooperativeKernel (grid 256x1024 = 1 block/CU,
// co-resident) + cg::this_grid().sync() -- device-scope fence makes
// cross-XCD dots visible; phase B = R7-verified top2 on the block's own 64
// tokens (threads 0..127). repack stays separate so ptt is written by a
// PRIOR dispatch (preserves s_load scalarization + K$ safety).

#define BB 8
#define SS 2048
#define DD 1024
#define EE 64
#define EPSV 1e-8f

// ---- K0: proto[e][d] -> ptt[d][e] -----------------------------------------
__global__ __launch_bounds__(256) void repack_proto(
    const float* __restrict__ proto, float* __restrict__ ptt) {
  const int gid = blockIdx.x * 256 + threadIdx.x;  // 0..65535
  const int d = gid >> 6;
  const int e = gid & 63;
  ptt[gid] = proto[(size_t)e * DD + d];
}

// ---- fused: normalized window dots + top2 ----------------------------------
// SMEM layout (floats):
//   [   0 .. 8703]  xt: 4 wk-groups x [2 buf][16 k][68 pad]
//   [8704 .. 8959]  nq: [4 wk][64 tok]
// Epilogue aliases B0 = SMEM[0..4095], B1 = SMEM[4096..8191] (dead xt).
__global__ __launch_bounds__(1024) void fused_router(
    const float* __restrict__ x, const float* __restrict__ ptt,
    float* __restrict__ dots, float* __restrict__ out) {
  __shared__ float SMEM[8960];

  const int tid  = threadIdx.x;
  const int lane = tid & 63;
  const int w    = __builtin_amdgcn_readfirstlane(tid >> 6);  // 0..15
  const int we   = w & 3;    // expert quad-group: experts [we*16, +16)
  const int wk   = w >> 2;   // K quarter: [wk*256, +256)
  const int b    = blockIdx.x >> 5;          // 8 batches
  const int s0   = (blockIdx.x & 31) * 64;   // 64 tokens per block

  // staging role within the wk-group (4 waves = 256 threads):
  const int gl = tid & 255;
  const int st = gl >> 2;    // staging token 0..63
  const int sq = gl & 3;     // staging k-quad 0..3 (4 consecutive k)

  float* xtw = SMEM + wk * 2176;   // [2][16][68]
  float* nqp = SMEM + 8704;        // [4][64]

  // lane-coalesced global source: 4 consecutive k of token st
  const float* xsrow =
      x + ((size_t)b * SS + s0 + st) * DD + wk * 256 + sq * 4;
  // wave-uniform proto slice base (scalarizes to s_load)
  const float* pr = ptt + (size_t)(wk * 256) * EE + we * 16;

  float4 acc0 = make_float4(0.f, 0.f, 0.f, 0.f);
  float4 acc1 = make_float4(0.f, 0.f, 0.f, 0.f);
  float4 acc2 = make_float4(0.f, 0.f, 0.f, 0.f);
  float4 acc3 = make_float4(0.f, 0.f, 0.f, 0.f);
  float q = 0.0f;

  // ---- prologue: stage chunk 0 into buf 0 (transpose [k][tok], pad 68) ----
  {
    const float4 v = *(const float4*)(xsrow);
    float* d = xtw + (sq * 4) * 68 + st;
    d[0]   = v.x;
    d[68]  = v.y;
    d[136] = v.z;
    d[204] = v.w;
  }
  __syncthreads();

  for (int c = 0; c < 16; ++c) {   // 16 chunks x 16 k = 256 k per wave
    const int buf = c & 1;
    // ---- issue next chunk's global load early ----
    float4 nv;
    if (c + 1 < 16) nv = *(const float4*)(xsrow + (c + 1) * 16);
    // ---- 16 k-steps: 1 ds_read_b32 + s_load'd proto + 16 fmac + 1 sumsq ----
    const float* xk_base = xtw + buf * 1088 + lane;
    const float* pp = pr + (size_t)(c * 16) * EE;
#pragma unroll
    for (int kk = 0; kk < 16; ++kk) {
      const float xk = xk_base[kk * 68];
      q += xk * xk;
      const float4 p0 = *(const float4*)(pp + kk * 64);
      const float4 p1 = *(const float4*)(pp + kk * 64 + 4);
      const float4 p2 = *(const float4*)(pp + kk * 64 + 8);
      const float4 p3 = *(const float4*)(pp + kk * 64 + 12);
      acc0.x += xk * p0.x; acc0.y += xk * p0.y;
      acc0.z += xk * p0.z; acc0.w += xk * p0.w;
      acc1.x += xk * p1.x; acc1.y += xk * p1.y;
      acc1.z += xk * p1.z; acc1.w += xk * p1.w;
      acc2.x += xk * p2.x; acc2.y += xk * p2.y;
      acc2.z += xk * p2.z; acc2.w += xk * p2.w;
      acc3.x += xk * p3.x; acc3.y += xk * p3.y;
      acc3.z += xk * p3.z; acc3.w += xk * p3.w;
    }
    // ---- write staged chunk into the other buffer ----
    if (c + 1 < 16) {
      float* d = xtw + (buf ^ 1) * 1088 + (sq * 4) * 68 + st;
      d[0]   = nv.x;
      d[68]  = nv.y;
      d[136] = nv.z;
      d[204] = nv.w;
    }
    __syncthreads();
  }

  // per-token sumsq partial for this K quarter (identical across we-waves)
  if (we == 0) nqp[wk * 64 + lane] = q;

  // epilogue tree buffers alias the (now dead) xt region.
  float* B0 = SMEM;
  float* B1 = SMEM + 4096;

#define WRB(R)                                              \
  { float* p_ = (R) + we * 1024 + lane * 4;                 \
    *(float4*)(p_ + 0)   = acc0;                            \
    *(float4*)(p_ + 256) = acc1;                            \
    *(float4*)(p_ + 512) = acc2;                            \
    *(float4*)(p_ + 768) = acc3; }
#define ADDB(R)                                             \
  { const float* p_ = (R) + we * 1024 + lane * 4;           \
    const float4 t0 = *(const float4*)(p_ + 0);             \
    const float4 t1 = *(const float4*)(p_ + 256);           \
    const float4 t2 = *(const float4*)(p_ + 512);           \
    const float4 t3 = *(const float4*)(p_ + 768);           \
    acc0.x += t0.x; acc0.y += t0.y; acc0.z += t0.z; acc0.w += t0.w; \
    acc1.x += t1.x; acc1.y += t1.y; acc1.z += t1.z; acc1.w += t1.w; \
    acc2.x += t2.x; acc2.y += t2.y; acc2.z += t2.z; acc2.w += t2.w; \
    acc3.x += t3.x; acc3.y += t3.y; acc3.z += t3.z; acc3.w += t3.w; }

  // deterministic tree over wk: (0+1) + (2+3)
  __syncthreads();
  if (wk == 1) WRB(B0)
  if (wk == 3) WRB(B1)
  __syncthreads();
  if (wk == 0) ADDB(B0)
  if (wk == 2) ADDB(B1)
  __syncthreads();
  if (wk == 2) WRB(B0)
  __syncthreads();
  if (wk == 0) {
    ADDB(B0)
    const float qs = nqp[lane] + nqp[64 + lane] +
                     nqp[128 + lane] + nqp[192 + lane];
    const float inv = 1.0f / fmaxf(sqrtf(qs), EPSV);
    acc0.x *= inv; acc0.y *= inv; acc0.z *= inv; acc0.w *= inv;
    acc1.x *= inv; acc1.y *= inv; acc1.z *= inv; acc1.w *= inv;
    acc2.x *= inv; acc2.y *= inv; acc2.z *= inv; acc2.w *= inv;
    acc3.x *= inv; acc3.y *= inv; acc3.z *= inv; acc3.w *= inv;
    float* dp = dots + ((size_t)b * SS + s0 + lane) * EE + we * 16;
    *(float4*)(dp)      = acc0;
    *(float4*)(dp + 4)  = acc1;
    *(float4*)(dp + 8)  = acc2;
    *(float4*)(dp + 12) = acc3;
  }

  // ==== phase B: window-3 + top-2 (R7-verified math) ========================
  cg::this_grid().sync();

#define T2UP(s, ei)                                            \
  if ((s) > v1) { v2 = v1; i2 = i1; v1 = (s); i1 = (ei); }     \
  else if ((s) > v2) { v2 = (s); i2 = (ei); }

  if (tid < 128) {
    const int sl = s0 + (tid >> 1);      // batch-local token
    const int h  = tid & 1;              // expert half (32 each)
    const int r0 = (sl >= 2) ? sl - 2 : 0;
    const int r1 = (sl >= 1) ? sl - 1 : 0;

    const float* d0 = dots + ((size_t)b * SS + r0) * EE + h * 32;
    const float* d1 = dots + ((size_t)b * SS + r1) * EE + h * 32;
    const float* d2 = dots + ((size_t)b * SS + sl) * EE + h * 32;

    float v1 = -INFINITY, v2 = -INFINITY;
    int i1 = 0, i2 = 0;
#pragma unroll
    for (int qd = 0; qd < 8; ++qd) {
      const float4 a = *(const float4*)(d0 + qd * 4);
      const float4 c = *(const float4*)(d1 + qd * 4);
      const float4 e = *(const float4*)(d2 + qd * 4);
      const int e0 = h * 32 + qd * 4;
      float s;
      s = a.x + c.x + e.x; T2UP(s, e0 + 0)
      s = a.y + c.y + e.y; T2UP(s, e0 + 1)
      s = a.z + c.z + e.z; T2UP(s, e0 + 2)
      s = a.w + c.w + e.w; T2UP(s, e0 + 3)
    }

    {  // merge the two halves (partner lane = lane^1); tie -> lower index
      const float ov1 = __shfl_xor(v1, 1);
      const int   oi1 = __shfl_xor(i1, 1);
      const float ov2 = __shfl_xor(v2, 1);
      const int   oi2 = __shfl_xor(i2, 1);
      const bool o_beats = (ov1 > v1) || (ov1 == v1 && oi1 < i1);
      if (o_beats) {
        const bool v1_beats_o2 = (v1 > ov2) || (v1 == ov2 && i1 < oi2);
        v2 = v1_beats_o2 ? v1 : ov2;
        i2 = v1_beats_o2 ? i1 : oi2;
        v1 = ov1;
        i1 = oi1;
      } else {
        const bool o1_beats_v2 = (ov1 > v2) || (ov1 == v2 && oi1 < i2);
        if (o1_beats_v2) { v2 = ov1; i2 = oi1; }
      }
    }

    if (h == 0) {
      const float ex = expf((v2 - v1) * (1.0f / 3.0f));  // <= 1
      const float w1 = 1.0f / (1.0f + ex);
      const size_t tokg = (size_t)b * SS + sl;
      const size_t o = tokg * 2;
      *(float2*)(out + o) = make_float2((float)i1, (float)i2);
      *(float2*)(out + (size_t)BB * SS * 2 + o) = make_float2(w1, ex * w1);
    }
  }
}

extern "C" void kernel_launch(void* const* d_in, const int* in_sizes, int n_in,
                              void* d_out, int out_size, void* d_ws, size_t ws_size,
                              hipStream_t stream) {
  const float* x     = (const float*)d_in[0];
  const float* proto = (const float*)d_in[1];
  // d_in[2] = attn_mask: unused by the reference output path.
  float* out  = (float*)d_out;
  float* ptt  = (float*)d_ws;                          // 256 KiB ptt[d][e]
  float* dots = (float*)((char*)d_ws + (512 << 10));   // 4 MiB normalized dots

  repack_proto<<<dim3(256), dim3(256), 0, stream>>>(proto, ptt);

  const float* xa = x;
  const float* pa = ptt;
  float* da = dots;
  float* oa = out;
  void* kargs[] = {(void*)&xa, (void*)&pa, (void*)&da, (void*)&oa};
  hipLaunchCooperativeKernel(fused_router, dim3(256), dim3(1024), kargs, 0,
                             stream);
}

// Round 8
// 129.744 us; speedup vs baseline: 1.3494x; 1.3494x over previous
//
#include <hip/hip_runtime.h>
#include <math.h>

// ClownSelector R17: R15 dots + pad-68 conflict fix; top2 parallelism x4.
//
// R16 post-mortem: cooperative fusion REFUTED -- fused kernel 80us (sync +
// phase-B ~32us inside), "rest" rose 80->92 (coop launch fights graph
// capture). But it decomposed the constant ~80us: top2 ~25-40us + repack
// ~3us + ~45us fixed harness overhead. So top2 is the attackable chunk,
// standalone, not via fusion.
//
// R17:
//  (1) dots: R15 structure verbatim (50us proven) with xt stride 64->68.
//      Staging write banks (sq*16 + j*4 + st)%32 collapse to 2-way (free,
//      m136); k-loop read (kk*68+lane)%32 stays 2-way. Kills the 1.57M
//      SQ_LDS_BANK_CONFLICT.
//  (2) top2: thread = (token, 8-expert oct) -> 131072 threads, grid
//      512x256 = 2 blocks/CU (old: 128 blocks = half GPU idle). 6
//      independent float4 loads/thread, then 3-step shfl_xor top-2 merge
//      (exact, order-independent, tie -> lower index preserved).
//      Window sum a+c+e per expert unchanged.

#define BB 8
#define SS 2048
#define DD 1024
#define EE 64
#define EPSV 1e-8f

// ---- K0: proto[e][d] -> ptt[d][e] -----------------------------------------
__global__ __launch_bounds__(256) void repack_proto(
    const float* __restrict__ proto, float* __restrict__ ptt) {
  const int gid = blockIdx.x * 256 + threadIdx.x;  // 0..65535
  const int d = gid >> 6;
  const int e = gid & 63;
  ptt[gid] = proto[(size_t)e * DD + d];
}

// ---- K1: normalized per-row dots ------------------------------------------
// SMEM layout (floats):
//   [   0 .. 8703]  xt: 4 wk-groups x [2 buf][16 k][68 pad]
//   [8704 .. 8959]  nq: [4 wk][64 tok]
// Epilogue aliases B0 = SMEM[0..4095], B1 = SMEM[4096..8191] (dead xt).
__global__ __launch_bounds__(1024) void router_dots(
    const float* __restrict__ x, const float* __restrict__ ptt,
    float* __restrict__ dots) {
  __shared__ float SMEM[8960];

  const int tid  = threadIdx.x;
  const int lane = tid & 63;
  const int w    = __builtin_amdgcn_readfirstlane(tid >> 6);  // 0..15
  const int we   = w & 3;    // expert quad-group: experts [we*16, +16)
  const int wk   = w >> 2;   // K quarter: [wk*256, +256)
  const int b    = blockIdx.x >> 5;          // 8 batches
  const int s0   = (blockIdx.x & 31) * 64;   // 64 tokens per block

  // staging role within the wk-group (4 waves = 256 threads):
  const int gl = tid & 255;
  const int st = gl >> 2;    // staging token 0..63
  const int sq = gl & 3;     // staging k-quad 0..3 (4 consecutive k)

  float* xtw = SMEM + wk * 2176;   // [2][16][68]
  float* nqp = SMEM + 8704;        // [4][64]

  // lane-coalesced global source: 4 consecutive k of token st
  const float* xsrow =
      x + ((size_t)b * SS + s0 + st) * DD + wk * 256 + sq * 4;
  // wave-uniform proto slice base (scalarizes to s_load)
  const float* pr = ptt + (size_t)(wk * 256) * EE + we * 16;

  float4 acc0 = make_float4(0.f, 0.f, 0.f, 0.f);
  float4 acc1 = make_float4(0.f, 0.f, 0.f, 0.f);
  float4 acc2 = make_float4(0.f, 0.f, 0.f, 0.f);
  float4 acc3 = make_float4(0.f, 0.f, 0.f, 0.f);
  float q = 0.0f;

  // ---- prologue: stage chunk 0 into buf 0 (transpose [k][tok], pad 68) ----
  {
    const float4 v = *(const float4*)(xsrow);
    float* d = xtw + (sq * 4) * 68 + st;
    d[0]   = v.x;
    d[68]  = v.y;
    d[136] = v.z;
    d[204] = v.w;
  }
  __syncthreads();

  for (int c = 0; c < 16; ++c) {   // 16 chunks x 16 k = 256 k per wave
    const int buf = c & 1;
    // ---- issue next chunk's global load early ----
    float4 nv;
    if (c + 1 < 16) nv = *(const float4*)(xsrow + (c + 1) * 16);
    // ---- 16 k-steps: 1 ds_read_b32 + s_load'd proto + 16 fmac + 1 sumsq ----
    const float* xk_base = xtw + buf * 1088 + lane;
    const float* pp = pr + (size_t)(c * 16) * EE;
#pragma unroll
    for (int kk = 0; kk < 16; ++kk) {
      const float xk = xk_base[kk * 68];
      q += xk * xk;
      const float4 p0 = *(const float4*)(pp + kk * 64);
      const float4 p1 = *(const float4*)(pp + kk * 64 + 4);
      const float4 p2 = *(const float4*)(pp + kk * 64 + 8);
      const float4 p3 = *(const float4*)(pp + kk * 64 + 12);
      acc0.x += xk * p0.x; acc0.y += xk * p0.y;
      acc0.z += xk * p0.z; acc0.w += xk * p0.w;
      acc1.x += xk * p1.x; acc1.y += xk * p1.y;
      acc1.z += xk * p1.z; acc1.w += xk * p1.w;
      acc2.x += xk * p2.x; acc2.y += xk * p2.y;
      acc2.z += xk * p2.z; acc2.w += xk * p2.w;
      acc3.x += xk * p3.x; acc3.y += xk * p3.y;
      acc3.z += xk * p3.z; acc3.w += xk * p3.w;
    }
    // ---- write staged chunk into the other buffer ----
    if (c + 1 < 16) {
      float* d = xtw + (buf ^ 1) * 1088 + (sq * 4) * 68 + st;
      d[0]   = nv.x;
      d[68]  = nv.y;
      d[136] = nv.z;
      d[204] = nv.w;
    }
    __syncthreads();
  }

  // per-token sumsq partial for this K quarter (identical across we-waves)
  if (we == 0) nqp[wk * 64 + lane] = q;

  // epilogue tree buffers alias the (now dead) xt region.
  float* B0 = SMEM;
  float* B1 = SMEM + 4096;

#define WRB(R)                                              \
  { float* p_ = (R) + we * 1024 + lane * 4;                 \
    *(float4*)(p_ + 0)   = acc0;                            \
    *(float4*)(p_ + 256) = acc1;                            \
    *(float4*)(p_ + 512) = acc2;                            \
    *(float4*)(p_ + 768) = acc3; }
#define ADDB(R)                                             \
  { const float* p_ = (R) + we * 1024 + lane * 4;           \
    const float4 t0 = *(const float4*)(p_ + 0);             \
    const float4 t1 = *(const float4*)(p_ + 256);           \
    const float4 t2 = *(const float4*)(p_ + 512);           \
    const float4 t3 = *(const float4*)(p_ + 768);           \
    acc0.x += t0.x; acc0.y += t0.y; acc0.z += t0.z; acc0.w += t0.w; \
    acc1.x += t1.x; acc1.y += t1.y; acc1.z += t1.z; acc1.w += t1.w; \
    acc2.x += t2.x; acc2.y += t2.y; acc2.z += t2.z; acc2.w += t2.w; \
    acc3.x += t3.x; acc3.y += t3.y; acc3.z += t3.z; acc3.w += t3.w; }

  // deterministic tree over wk: (0+1) + (2+3)
  __syncthreads();
  if (wk == 1) WRB(B0)
  if (wk == 3) WRB(B1)
  __syncthreads();
  if (wk == 0) ADDB(B0)
  if (wk == 2) ADDB(B1)
  __syncthreads();
  if (wk == 2) WRB(B0)
  __syncthreads();
  if (wk == 0) {
    ADDB(B0)
    const float qs = nqp[lane] + nqp[64 + lane] +
                     nqp[128 + lane] + nqp[192 + lane];
    const float inv = 1.0f / fmaxf(sqrtf(qs), EPSV);
    acc0.x *= inv; acc0.y *= inv; acc0.z *= inv; acc0.w *= inv;
    acc1.x *= inv; acc1.y *= inv; acc1.z *= inv; acc1.w *= inv;
    acc2.x *= inv; acc2.y *= inv; acc2.z *= inv; acc2.w *= inv;
    acc3.x *= inv; acc3.y *= inv; acc3.z *= inv; acc3.w *= inv;
    float* dp = dots + ((size_t)b * SS + s0 + lane) * EE + we * 16;
    *(float4*)(dp)      = acc0;
    *(float4*)(dp + 4)  = acc1;
    *(float4*)(dp + 8)  = acc2;
    *(float4*)(dp + 12) = acc3;
  }
}

// ---- K2: window-3 + top-2 + renorm softmax, oct-per-thread -----------------
#define T2UP(s, ei)                                            \
  if ((s) > v1) { v2 = v1; i2 = i1; v1 = (s); i1 = (ei); }     \
  else if ((s) > v2) { v2 = (s); i2 = (ei); }

__global__ __launch_bounds__(256) void router_top2(
    const float* __restrict__ dots, float* __restrict__ out) {
  const int gtid = blockIdx.x * 256 + threadIdx.x;  // 0..131071
  const int tok  = gtid >> 3;          // global token
  const int h    = gtid & 7;           // expert oct (8 experts each)
  const int b    = tok >> 11;
  const int sl   = tok & (SS - 1);
  const int r0   = (sl >= 2) ? sl - 2 : 0;   // causal pad: replicate token 0
  const int r1   = (sl >= 1) ? sl - 1 : 0;

  const float* d0 = dots + ((size_t)b * SS + r0) * EE + h * 8;
  const float* d1 = dots + ((size_t)b * SS + r1) * EE + h * 8;
  const float* d2 = dots + ((size_t)b * SS + sl) * EE + h * 8;

  float v1 = -INFINITY, v2 = -INFINITY;
  int i1 = 0, i2 = 0;
#pragma unroll
  for (int qd = 0; qd < 2; ++qd) {
    const float4 a = *(const float4*)(d0 + qd * 4);
    const float4 c = *(const float4*)(d1 + qd * 4);
    const float4 e = *(const float4*)(d2 + qd * 4);
    const int e0 = h * 8 + qd * 4;
    float s;
    s = a.x + c.x + e.x; T2UP(s, e0 + 0)
    s = a.y + c.y + e.y; T2UP(s, e0 + 1)
    s = a.z + c.z + e.z; T2UP(s, e0 + 2)
    s = a.w + c.w + e.w; T2UP(s, e0 + 3)
  }

  // merge the 8 octs (partners lane^1, lane^2, lane^4); tie -> lower index
#pragma unroll
  for (int m = 1; m <= 4; m <<= 1) {
    const float ov1 = __shfl_xor(v1, m);
    const int   oi1 = __shfl_xor(i1, m);
    const float ov2 = __shfl_xor(v2, m);
    const int   oi2 = __shfl_xor(i2, m);
    const bool o_beats = (ov1 > v1) || (ov1 == v1 && oi1 < i1);
    if (o_beats) {
      const bool v1_beats_o2 = (v1 > ov2) || (v1 == ov2 && i1 < oi2);
      v2 = v1_beats_o2 ? v1 : ov2;
      i2 = v1_beats_o2 ? i1 : oi2;
      v1 = ov1;
      i1 = oi1;
    } else {
      const bool o1_beats_v2 = (ov1 > v2) || (ov1 == v2 && oi1 < i2);
      if (o1_beats_v2) { v2 = ov1; i2 = oi1; }
    }
  }

  if (h == 0) {
    const float ex = expf((v2 - v1) * (1.0f / 3.0f));  // <= 1
    const float w1 = 1.0f / (1.0f + ex);
    const size_t o = (size_t)tok * 2;
    *(float2*)(out + o) = make_float2((float)i1, (float)i2);
    *(float2*)(out + (size_t)BB * SS * 2 + o) = make_float2(w1, ex * w1);
  }
}

extern "C" void kernel_launch(void* const* d_in, const int* in_sizes, int n_in,
                              void* d_out, int out_size, void* d_ws, size_t ws_size,
                              hipStream_t stream) {
  const float* x     = (const float*)d_in[0];
  const float* proto = (const float*)d_in[1];
  // d_in[2] = attn_mask: unused by the reference output path.
  float* out  = (float*)d_out;
  float* ptt  = (float*)d_ws;                          // 256 KiB ptt[d][e]
  float* dots = (float*)((char*)d_ws + (512 << 10));   // 4 MiB normalized dots

  repack_proto<<<dim3(256), dim3(256), 0, stream>>>(proto, ptt);
  router_dots<<<dim3(256), dim3(1024), 0, stream>>>(x, ptt, dots);
  router_top2<<<dim3(512), dim3(256), 0, stream>>>(dots, out);
}

// Round 9
// 126.829 us; speedup vs baseline: 1.3804x; 1.0230x over previous
//
#include <hip/hip_runtime.h>
#include <math.h>

// ClownSelector R18: 8tok x 8exp lane tile -- halve DS cost per FLOP.
//
// R17 post-mortem: pad-68 cut conflicts 3x but rd stayed 51us (b128 has an
// inherent 8-slot/bank floor; conflicts weren't binding). R13 (43us) is
// DS-bound: 3 b128/kstep for 32 fmac -> per-CU DS 74Kcyc (31us) vs VALU
// 33Kcyc/SIMD (14us). DS is ONE pipe/CU, VALU is FOUR.
//
// R18: lane tile 8 tok x 8 exp (64 fmac/kstep) with 4 b128 reads/kstep ->
// DS per fmac halves: per-CU DS ~41Kcyc reads (+staging ~ 21us total) vs
// VALU 15us -> predicted rd 28-33us. Construction from proven parts only:
//  - 8 waves x 128-k slices, k ascending + R13's exact pairwise tree
//    (summation order per (t,e) unchanged from R13).
//  - CK=8 chunks: prefetch = 4 float4 (16 VGPR); total live ~112 < 128
//    (R12/R14 spill lesson).
//  - single-buffered wave-private xt AND pt (R12/R13-proven: per-wave DS
//    in-order => WAR to same buffer hazard-free, zero barriers in k-loop).
//  - x staged transposed [8k][68] (2-way banks, free); proto [8k][64].
//  - lane = token for staging => sumsq folds in, no shfl.
//  - epilogue tree B0/B1 alias dead xt+pt regions.
// top2 (oct-per-thread, grid 512) and repack: R17 verbatim.
// Canary: WRITE_SIZE >> 4MB = spill => revert to R13-dots + R17-top2.

#define BB 8
#define SS 2048
#define DD 1024
#define EE 64
#define EPSV 1e-8f

#define FMA4(A, s, P) \
  A.x += (s) * (P).x; A.y += (s) * (P).y; A.z += (s) * (P).z; A.w += (s) * (P).w;

#define SUMSQ4(v) ((v).x * (v).x + (v).y * (v).y + (v).z * (v).z + (v).w * (v).w)

// ---- K0: proto[e][d] -> ptt[d][e] -----------------------------------------
__global__ __launch_bounds__(256) void repack_proto(
    const float* __restrict__ proto, float* __restrict__ ptt) {
  const int gid = blockIdx.x * 256 + threadIdx.x;  // 0..65535
  const int d = gid >> 6;
  const int e = gid & 63;
  ptt[gid] = proto[(size_t)e * DD + d];
}

// ---- K1: normalized per-row dots ------------------------------------------
// SMEM layout (floats):
//   [   0 .. 4351]  xt: 8 waves x [8 k][68 pad]   (single-buffered)
//   [4352 .. 8447]  pt: 8 waves x [8 k][64 e]     (single-buffered)
//   [8704 .. 9215]  nq: [8 wave][64 tok]
// Epilogue aliases B0 = SMEM[0..4351], B1 = SMEM[4352..8703] (dead regions).
__global__ __launch_bounds__(512) void router_dots(
    const float* __restrict__ x, const float* __restrict__ ptt,
    float* __restrict__ dots) {
  __shared__ float SMEM[9216];

  const int tid  = threadIdx.x;
  const int lane = tid & 63;
  const int w    = __builtin_amdgcn_readfirstlane(tid >> 6);  // 0..7
  const int eg   = lane & 7;   // experts [eg*8, +8)
  const int tg   = lane >> 3;  // tokens  [tg*8, +8)
  const int b    = blockIdx.x >> 5;          // 8 batches
  const int s0   = (blockIdx.x & 31) * 64;   // 64 tokens per block

  float* xtw = SMEM + w * 544;           // [8][68]
  float* ptw = SMEM + 4352 + w * 512;    // [8][64]
  float* nqp = SMEM + 8704;              // [8][64]

  const int kbase = w * 128;   // this wave's k-slice (128 wide)
  // staging sources: lane stages token `lane` (x) / 4 floats (proto)
  const float* xsrow = x + ((size_t)b * SS + s0 + lane) * DD + kbase;
  const float* psrow = ptt + (size_t)kbase * EE + lane * 4;

  float4 accA0[4], accA1[4], accB0[4], accB1[4];
#pragma unroll
  for (int i = 0; i < 4; ++i) {
    accA0[i] = make_float4(0.f, 0.f, 0.f, 0.f);
    accA1[i] = make_float4(0.f, 0.f, 0.f, 0.f);
    accB0[i] = make_float4(0.f, 0.f, 0.f, 0.f);
    accB1[i] = make_float4(0.f, 0.f, 0.f, 0.f);
  }
  float q = 0.0f;

  // ---- prologue: stage chunk 0 (x transposed + proto) ----
  {
    const float4 v0 = *(const float4*)(xsrow);
    const float4 v1 = *(const float4*)(xsrow + 4);
    const float4 r0 = *(const float4*)(psrow);
    const float4 r1 = *(const float4*)(psrow + 256);
    q += SUMSQ4(v0) + SUMSQ4(v1);
    float* d = xtw + lane;
    d[0]   = v0.x; d[68]  = v0.y; d[136] = v0.z; d[204] = v0.w;
    d[272] = v1.x; d[340] = v1.y; d[408] = v1.z; d[476] = v1.w;
    *(float4*)(ptw + lane * 4)       = r0;
    *(float4*)(ptw + 256 + lane * 4) = r1;
  }

  const float* xc = xtw + tg * 8;   // + kk*68
  const float* pc = ptw + eg * 8;   // + kk*64

  for (int c = 0; c < 16; ++c) {   // 16 chunks x 8 k = 128 k per wave
    // ---- prefetch next chunk (consumed after the k-loop) ----
    float4 v0, v1, r0, r1;
    if (c + 1 < 16) {
      v0 = *(const float4*)(xsrow + (c + 1) * 8);
      v1 = *(const float4*)(xsrow + (c + 1) * 8 + 4);
      r0 = *(const float4*)(psrow + (c + 1) * 512);
      r1 = *(const float4*)(psrow + (c + 1) * 512 + 256);
    }
    // ---- 8 k-steps: 2 b128 (x, 8 tok) + 2 b128 (proto, 8 exp) + 64 fmac ----
#pragma unroll
    for (int kk = 0; kk < 8; ++kk) {
      const float4 xfA = *(const float4*)(xc + kk * 68);
      const float4 xfB = *(const float4*)(xc + kk * 68 + 4);
      const float4 p0  = *(const float4*)(pc + kk * 64);
      const float4 p1  = *(const float4*)(pc + kk * 64 + 4);
      FMA4(accA0[0], xfA.x, p0) FMA4(accA1[0], xfA.x, p1)
      FMA4(accA0[1], xfA.y, p0) FMA4(accA1[1], xfA.y, p1)
      FMA4(accA0[2], xfA.z, p0) FMA4(accA1[2], xfA.z, p1)
      FMA4(accA0[3], xfA.w, p0) FMA4(accA1[3], xfA.w, p1)
      FMA4(accB0[0], xfB.x, p0) FMA4(accB1[0], xfB.x, p1)
      FMA4(accB0[1], xfB.y, p0) FMA4(accB1[1], xfB.y, p1)
      FMA4(accB0[2], xfB.z, p0) FMA4(accB1[2], xfB.z, p1)
      FMA4(accB0[3], xfB.w, p0) FMA4(accB1[3], xfB.w, p1)
    }
    // ---- stage prefetched chunk (same buffers; wave-private DS in-order) ----
    if (c + 1 < 16) {
      q += SUMSQ4(v0) + SUMSQ4(v1);
      float* d = xtw + lane;
      d[0]   = v0.x; d[68]  = v0.y; d[136] = v0.z; d[204] = v0.w;
      d[272] = v1.x; d[340] = v1.y; d[408] = v1.z; d[476] = v1.w;
      *(float4*)(ptw + lane * 4)       = r0;
      *(float4*)(ptw + 256 + lane * 4) = r1;
    }
  }

  // per-token (lane) sumsq partial for this wave's 128-k slice
  nqp[w * 64 + lane] = q;

  // epilogue tree buffers alias the (now dead) xt+pt regions: [64][68]
  float* B0 = SMEM;
  float* B1 = SMEM + 4352;

#define WRB(R)                                                        \
  { _Pragma("unroll") for (int i = 0; i < 4; ++i) {                   \
      float* pA_ = (R) + (tg * 8 + i) * 68 + eg * 8;                  \
      float* pB_ = (R) + (tg * 8 + 4 + i) * 68 + eg * 8;              \
      *(float4*)(pA_)     = accA0[i];                                 \
      *(float4*)(pA_ + 4) = accA1[i];                                 \
      *(float4*)(pB_)     = accB0[i];                                 \
      *(float4*)(pB_ + 4) = accB1[i]; } }
#define ADDB(R)                                                       \
  { _Pragma("unroll") for (int i = 0; i < 4; ++i) {                   \
      const float* pA_ = (R) + (tg * 8 + i) * 68 + eg * 8;            \
      const float* pB_ = (R) + (tg * 8 + 4 + i) * 68 + eg * 8;        \
      const float4 tA0 = *(const float4*)(pA_);                       \
      const float4 tA1 = *(const float4*)(pA_ + 4);                   \
      const float4 tB0 = *(const float4*)(pB_);                       \
      const float4 tB1 = *(const float4*)(pB_ + 4);                   \
      accA0[i].x += tA0.x; accA0[i].y += tA0.y;                       \
      accA0[i].z += tA0.z; accA0[i].w += tA0.w;                       \
      accA1[i].x += tA1.x; accA1[i].y += tA1.y;                       \
      accA1[i].z += tA1.z; accA1[i].w += tA1.w;                       \
      accB0[i].x += tB0.x; accB0[i].y += tB0.y;                       \
      accB0[i].z += tB0.z; accB0[i].w += tB0.w;                       \
      accB1[i].x += tB1.x; accB1[i].y += tB1.y;                       \
      accB1[i].z += tB1.z; accB1[i].w += tB1.w; } }

  // deterministic tree over 8 waves (R13's exact sequence)
  __syncthreads();
  if (w == 1) WRB(B0)
  if (w == 5) WRB(B1)
  __syncthreads();
  if (w == 0) ADDB(B0)
  if (w == 4) ADDB(B1)
  __syncthreads();
  if (w == 3) WRB(B0)
  if (w == 7) WRB(B1)
  __syncthreads();
  if (w == 2) ADDB(B0)
  if (w == 6) ADDB(B1)
  __syncthreads();
  if (w == 2) WRB(B0)
  if (w == 6) WRB(B1)
  __syncthreads();
  if (w == 0) ADDB(B0)
  if (w == 4) ADDB(B1)
  __syncthreads();
  if (w == 4) WRB(B0)
  __syncthreads();
  if (w == 0) {
    ADDB(B0)
#pragma unroll
    for (int i = 0; i < 4; ++i) {
      const int rA = tg * 8 + i;
      const int rB = rA + 4;
      float qsA = 0.0f, qsB = 0.0f;
#pragma unroll
      for (int ww = 0; ww < 8; ++ww) {
        qsA += nqp[ww * 64 + rA];
        qsB += nqp[ww * 64 + rB];
      }
      const float invA = 1.0f / fmaxf(sqrtf(qsA), EPSV);
      const float invB = 1.0f / fmaxf(sqrtf(qsB), EPSV);
      float4 oA0 = accA0[i], oA1 = accA1[i], oB0 = accB0[i], oB1 = accB1[i];
      oA0.x *= invA; oA0.y *= invA; oA0.z *= invA; oA0.w *= invA;
      oA1.x *= invA; oA1.y *= invA; oA1.z *= invA; oA1.w *= invA;
      oB0.x *= invB; oB0.y *= invB; oB0.z *= invB; oB0.w *= invB;
      oB1.x *= invB; oB1.y *= invB; oB1.z *= invB; oB1.w *= invB;
      float* dpA = dots + ((size_t)b * SS + s0 + rA) * EE + eg * 8;
      float* dpB = dots + ((size_t)b * SS + s0 + rB) * EE + eg * 8;
      *(float4*)(dpA)     = oA0;
      *(float4*)(dpA + 4) = oA1;
      *(float4*)(dpB)     = oB0;
      *(float4*)(dpB + 4) = oB1;
    }
  }
}

// ---- K2: window-3 + top-2 + renorm softmax, oct-per-thread (R17) -----------
#define T2UP(s, ei)                                            \
  if ((s) > v1) { v2 = v1; i2 = i1; v1 = (s); i1 = (ei); }     \
  else if ((s) > v2) { v2 = (s); i2 = (ei); }

__global__ __launch_bounds__(256) void router_top2(
    const float* __restrict__ dots, float* __restrict__ out) {
  const int gtid = blockIdx.x * 256 + threadIdx.x;  // 0..131071
  const int tok  = gtid >> 3;          // global token
  const int h    = gtid & 7;           // expert oct (8 experts each)
  const int b    = tok >> 11;
  const int sl   = tok & (SS - 1);
  const int r0   = (sl >= 2) ? sl - 2 : 0;   // causal pad: replicate token 0
  const int r1   = (sl >= 1) ? sl - 1 : 0;

  const float* d0 = dots + ((size_t)b * SS + r0) * EE + h * 8;
  const float* d1 = dots + ((size_t)b * SS + r1) * EE + h * 8;
  const float* d2 = dots + ((size_t)b * SS + sl) * EE + h * 8;

  float v1 = -INFINITY, v2 = -INFINITY;
  int i1 = 0, i2 = 0;
#pragma unroll
  for (int qd = 0; qd < 2; ++qd) {
    const float4 a = *(const float4*)(d0 + qd * 4);
    const float4 c = *(const float4*)(d1 + qd * 4);
    const float4 e = *(const float4*)(d2 + qd * 4);
    const int e0 = h * 8 + qd * 4;
    float s;
    s = a.x + c.x + e.x; T2UP(s, e0 + 0)
    s = a.y + c.y + e.y; T2UP(s, e0 + 1)
    s = a.z + c.z + e.z; T2UP(s, e0 + 2)
    s = a.w + c.w + e.w; T2UP(s, e0 + 3)
  }

  // merge the 8 octs (partners lane^1, lane^2, lane^4); tie -> lower index
#pragma unroll
  for (int m = 1; m <= 4; m <<= 1) {
    const float ov1 = __shfl_xor(v1, m);
    const int   oi1 = __shfl_xor(i1, m);
    const float ov2 = __shfl_xor(v2, m);
    const int   oi2 = __shfl_xor(i2, m);
    const bool o_beats = (ov1 > v1) || (ov1 == v1 && oi1 < i1);
    if (o_beats) {
      const bool v1_beats_o2 = (v1 > ov2) || (v1 == ov2 && i1 < oi2);
      v2 = v1_beats_o2 ? v1 : ov2;
      i2 = v1_beats_o2 ? i1 : oi2;
      v1 = ov1;
      i1 = oi1;
    } else {
      const bool o1_beats_v2 = (ov1 > v2) || (ov1 == v2 && oi1 < i2);
      if (o1_beats_v2) { v2 = ov1; i2 = oi1; }
    }
  }

  if (h == 0) {
    const float ex = expf((v2 - v1) * (1.0f / 3.0f));  // <= 1
    const float w1 = 1.0f / (1.0f + ex);
    const size_t o = (size_t)tok * 2;
    *(float2*)(out + o) = make_float2((float)i1, (float)i2);
    *(float2*)(out + (size_t)BB * SS * 2 + o) = make_float2(w1, ex * w1);
  }
}

extern "C" void kernel_launch(void* const* d_in, const int* in_sizes, int n_in,
                              void* d_out, int out_size, void* d_ws, size_t ws_size,
                              hipStream_t stream) {
  const float* x     = (const float*)d_in[0];
  const float* proto = (const float*)d_in[1];
  // d_in[2] = attn_mask: unused by the reference output path.
  float* out  = (float*)d_out;
  float* ptt  = (float*)d_ws;                          // 256 KiB ptt[d][e]
  float* dots = (float*)((char*)d_ws + (512 << 10));   // 4 MiB normalized dots

  repack_proto<<<dim3(256), dim3(256), 0, stream>>>(proto, ptt);
  router_dots<<<dim3(256), dim3(512), 0, stream>>>(x, ptt, dots);
  router_top2<<<dim3(512), dim3(256), 0, stream>>>(dots, out);
}